// Round 4
// baseline (907.975 us; speedup 1.0000x reference)
//
#include <hip/hip_runtime.h>

typedef unsigned short u16;
typedef __bf16 bf16x8 __attribute__((ext_vector_type(8)));
typedef float f32x4 __attribute__((ext_vector_type(4)));

#define HID 1280
#define NHEADS 20
#define FFD 5120

__device__ __forceinline__ u16 f2b(float f) {
  union { float f; unsigned u; } a; a.f = f;
  unsigned r = a.u + 0x7FFFu + ((a.u >> 16) & 1u);
  return (u16)(r >> 16);
}

__device__ __forceinline__ void g2lds16(const void* g, void* l) {
  __builtin_amdgcn_global_load_lds(
      (__attribute__((address_space(1))) void*)(g),
      (__attribute__((address_space(3))) void*)(l), 16, 0, 0);
}

// XCD-aware block remap: MI355X round-robins workgroups over 8 XCDs
// (block id % 8 = XCD). Give each XCD a CONTIGUOUS chunk of tile space,
// decoded column-major (row fastest), so each XCD's weight column-stripe
// stays resident in its private 4 MiB L2.
__device__ __forceinline__ void swz(int& bx, int& by) {
  int nx = gridDim.x, ny = gridDim.y;
  int nb = nx * ny;
  int id = blockIdx.y * nx + blockIdx.x;
  if ((nb & 7) == 0) {
    int xcd = id & 7;
    int slot = id >> 3;
    int t = xcd * (nb >> 3) + slot;
    bx = t / ny;
    by = t - bx * ny;
  } else {
    bx = blockIdx.x;
    by = blockIdx.y;
  }
}

// ---------------------------------------------------------------------------
struct CvtArgs {
  const float* src[10];
  u16* dst[10];
  int cum4[11];
};

__global__ __launch_bounds__(256) void cvt_weights(CvtArgs a, int total4) {
  int i = blockIdx.x * 256 + threadIdx.x;
  if (i >= total4) return;
  int seg = 0;
#pragma unroll
  for (int s = 1; s < 10; s++) seg += (i >= a.cum4[s]);
  int j = (i - a.cum4[seg]) * 4;
  float4 f = *(const float4*)(a.src[seg] + j);
  union { unsigned long long u; u16 s[4]; } o;
  o.s[0] = f2b(f.x); o.s[1] = f2b(f.y); o.s[2] = f2b(f.z); o.s[3] = f2b(f.w);
  *(unsigned long long*)(a.dst[seg] + j) = o.u;
}

__global__ __launch_bounds__(256) void cvt_enc(const float* __restrict__ enc,
                                               u16* __restrict__ encp) {
  int i = blockIdx.x * 256 + threadIdx.x;
  int j = i * 4;
  int row = j >> 11;
  unsigned long long out = 0ull;
  if (row < 154) {
    float4 f = *(const float4*)(enc + j);
    union { unsigned long long u; u16 s[4]; } o;
    o.s[0] = f2b(f.x); o.s[1] = f2b(f.y); o.s[2] = f2b(f.z); o.s[3] = f2b(f.w);
    out = o.u;
  }
  *(unsigned long long*)(encp + j) = out;
}

// ---------------------------------------------------------------------------
__global__ __launch_bounds__(256) void ln_bf16(const float* __restrict__ X,
                                               const float* __restrict__ g,
                                               const float* __restrict__ bta,
                                               u16* __restrict__ Out) {
  const int row = blockIdx.x, tid = threadIdx.x;
  const float* xr = X + (size_t)row * HID;
  float v[5];
#pragma unroll
  for (int i = 0; i < 5; i++) v[i] = xr[tid + i * 256];
  float s = v[0] + v[1] + v[2] + v[3] + v[4];
#pragma unroll
  for (int off = 32; off >= 1; off >>= 1) s += __shfl_down(s, off);
  __shared__ float red[4];
  if ((tid & 63) == 0) red[tid >> 6] = s;
  __syncthreads();
  float mu = (red[0] + red[1] + red[2] + red[3]) * (1.0f / HID);
  float d = 0.f;
#pragma unroll
  for (int i = 0; i < 5; i++) { float t = v[i] - mu; d += t * t; }
#pragma unroll
  for (int off = 32; off >= 1; off >>= 1) d += __shfl_down(d, off);
  __syncthreads();
  if ((tid & 63) == 0) red[tid >> 6] = d;
  __syncthreads();
  float rstd = rsqrtf((red[0] + red[1] + red[2] + red[3]) * (1.0f / HID) + 1e-5f);
#pragma unroll
  for (int i = 0; i < 5; i++) {
    int c = tid + i * 256;
    Out[(size_t)row * HID + c] = f2b((v[i] - mu) * rstd * g[c] + bta[c]);
  }
}

// ---------------------------------------------------------------------------
// bf16 GEMM, C = A * W^T. 128x128 tile, BK=32. LDS granule swizzle
// f(row) = (row>>1)&3: phys granule p of row r holds logical granule
// p ^ f(r). Quad's 16 lanes then map 2-to-1 onto the 8 bank-groups
// (2-way = free); the round-2 f=row&3 left a 4-way conflict.
// ---------------------------------------------------------------------------
__global__ __launch_bounds__(256) void gemm_bt(
    const u16* __restrict__ A, const u16* __restrict__ Bw,
    u16* __restrict__ Cb, float* __restrict__ Cf,
    const float* __restrict__ bias, const float* __restrict__ resid,
    int M, int N, int K, int mode, int nsplit) {
  __shared__ u16 As[4096];
  __shared__ u16 Bs[4096];
  const int tid = threadIdx.x;
  const int wid = tid >> 6, lane = tid & 63;
  const int quad = lane >> 4, l16 = lane & 15;
  int bx, by; swz(bx, by);
  const int bm = by * 128, bn = bx * 128;
  const int wm = (wid & 1) * 64, wn = (wid >> 1) * 64;

  const int arow = tid >> 2;
  const int acol = (((tid & 3) ^ ((tid >> 3) & 3)) * 8);  // src granule, swizzled
  const u16* Ag0 = A + (size_t)(bm + arow) * K + acol;
  const u16* Ag1 = A + (size_t)(bm + 64 + arow) * K + acol;
  const u16* Bg0 = Bw + (size_t)(bn + arow) * K + acol;
  const u16* Bg1 = Bw + (size_t)(bn + 64 + arow) * K + acol;
  u16* ldsA0 = &As[wid * 512];
  u16* ldsA1 = &As[2048 + wid * 512];
  u16* ldsB0 = &Bs[wid * 512];
  u16* ldsB1 = &Bs[2048 + wid * 512];

  f32x4 acc[4][4] = {};
  const int fsw = (quad ^ ((l16 >> 1) & 3)) * 8;

  for (int k0 = 0; k0 < K; k0 += 32) {
    __syncthreads();
    g2lds16(Ag0 + k0, ldsA0);
    g2lds16(Ag1 + k0, ldsA1);
    g2lds16(Bg0 + k0, ldsB0);
    g2lds16(Bg1 + k0, ldsB1);
    __syncthreads();
    bf16x8 af[4], bfr[4];
#pragma unroll
    for (int mt = 0; mt < 4; mt++)
      af[mt] = *(const bf16x8*)&As[(wm + mt * 16 + l16) * 32 + fsw];
#pragma unroll
    for (int nt = 0; nt < 4; nt++)
      bfr[nt] = *(const bf16x8*)&Bs[(wn + nt * 16 + l16) * 32 + fsw];
#pragma unroll
    for (int mt = 0; mt < 4; mt++)
#pragma unroll
      for (int nt = 0; nt < 4; nt++)
        acc[mt][nt] = __builtin_amdgcn_mfma_f32_16x16x32_bf16(af[mt], bfr[nt], acc[mt][nt], 0, 0, 0);
  }

  if (mode == 0) {
#pragma unroll
    for (int mt = 0; mt < 4; mt++)
#pragma unroll
      for (int nt = 0; nt < 4; nt++)
#pragma unroll
        for (int r = 0; r < 4; r++) {
          int row = bm + wm + mt * 16 + quad * 4 + r;
          int col = bn + wn + nt * 16 + l16;
          u16 val = f2b(acc[mt][nt][r]);
          if (nsplit > 0) {
            int t = (col >= 2 * nsplit) ? 2 : ((col >= nsplit) ? 1 : 0);
            int dc = col - t * nsplit;
            Cb[(size_t)t * M * nsplit + (size_t)row * nsplit + dc] = val;
          } else {
            Cb[(size_t)row * N + col] = val;
          }
        }
  } else {
#pragma unroll
    for (int mt = 0; mt < 4; mt++)
#pragma unroll
      for (int nt = 0; nt < 4; nt++)
#pragma unroll
        for (int r = 0; r < 4; r++) {
          int row = bm + wm + mt * 16 + quad * 4 + r;
          int col = bn + wn + nt * 16 + l16;
          size_t idx = (size_t)row * N + col;
          Cf[idx] = acc[mt][nt][r] + bias[col] + resid[idx];
        }
  }
}

// ---------------------------------------------------------------------------
// GEGLU GEMM: 128M x 64N, dual accumulators, same LDS swizzle.
// ---------------------------------------------------------------------------
__global__ __launch_bounds__(256) void gemm_geglu(
    const u16* __restrict__ A, const u16* __restrict__ W,
    const float* __restrict__ bias, u16* __restrict__ Out,
    int M, int K) {
  __shared__ u16 As[4096];
  __shared__ u16 B1s[2048];
  __shared__ u16 B2s[2048];
  const int tid = threadIdx.x;
  const int wid = tid >> 6, lane = tid & 63;
  const int quad = lane >> 4, l16 = lane & 15;
  int bx, by; swz(bx, by);
  const int bm = by * 128, bn = bx * 64;
  const int wm = (wid & 1) * 64, wn = (wid >> 1) * 32;

  const int arow = tid >> 2;
  const int acol = (((tid & 3) ^ ((tid >> 3) & 3)) * 8);
  const u16* Ag0 = A + (size_t)(bm + arow) * K + acol;
  const u16* Ag1 = A + (size_t)(bm + 64 + arow) * K + acol;
  const u16* B1g = W + (size_t)(bn + arow) * K + acol;
  const u16* B2g = W + (size_t)(FFD + bn + arow) * K + acol;

  f32x4 acc1[4][2] = {};
  f32x4 acc2[4][2] = {};
  const int fsw = (quad ^ ((l16 >> 1) & 3)) * 8;

  for (int k0 = 0; k0 < K; k0 += 32) {
    __syncthreads();
    g2lds16(Ag0 + k0, &As[wid * 512]);
    g2lds16(Ag1 + k0, &As[2048 + wid * 512]);
    g2lds16(B1g + k0, &B1s[wid * 512]);
    g2lds16(B2g + k0, &B2s[wid * 512]);
    __syncthreads();
    bf16x8 af[4], b1[2], b2[2];
#pragma unroll
    for (int mt = 0; mt < 4; mt++)
      af[mt] = *(const bf16x8*)&As[(wm + mt * 16 + l16) * 32 + fsw];
#pragma unroll
    for (int nt = 0; nt < 2; nt++) {
      b1[nt] = *(const bf16x8*)&B1s[(wn + nt * 16 + l16) * 32 + fsw];
      b2[nt] = *(const bf16x8*)&B2s[(wn + nt * 16 + l16) * 32 + fsw];
    }
#pragma unroll
    for (int mt = 0; mt < 4; mt++)
#pragma unroll
      for (int nt = 0; nt < 2; nt++) {
        acc1[mt][nt] = __builtin_amdgcn_mfma_f32_16x16x32_bf16(af[mt], b1[nt], acc1[mt][nt], 0, 0, 0);
        acc2[mt][nt] = __builtin_amdgcn_mfma_f32_16x16x32_bf16(af[mt], b2[nt], acc2[mt][nt], 0, 0, 0);
      }
  }

#pragma unroll
  for (int mt = 0; mt < 4; mt++)
#pragma unroll
    for (int nt = 0; nt < 2; nt++)
#pragma unroll
      for (int r = 0; r < 4; r++) {
        int row = bm + wm + mt * 16 + quad * 4 + r;
        int col = bn + wn + nt * 16 + l16;
        float v1 = acc1[mt][nt][r] + bias[col];
        float v2 = acc2[mt][nt][r] + bias[FFD + col];
        float ge = 0.5f * v2 * (1.0f + erff(v2 * 0.70710678118654752440f));
        Out[(size_t)row * FFD + col] = f2b(v1 * ge);
      }
}

// ---------------------------------------------------------------------------
// Flash attention v2: KV tile = 128, all LDS XOR-granule-swizzled,
// K staged via global_load_lds, row-sum via ones-MFMA.
// ---------------------------------------------------------------------------
#define BS 128
__global__ __launch_bounds__(256) void flash_attn(
    const u16* __restrict__ Q, const u16* __restrict__ Kb,
    const u16* __restrict__ Vb, u16* __restrict__ O,
    int T, int Sv, float scale) {
  __shared__ u16 Ks[BS * 64];     // [s][d], phys granule = g ^ (s&7)
  __shared__ u16 Vt[64 * BS];     // [d][s], phys granule = g ^ (((d>>3)^d)&7)
  __shared__ u16 Ps[4][16 * BS];  // per-wave P, phys granule = g ^ (row&7)
  const int tid = threadIdx.x, wid = tid >> 6, lane = tid & 63;
  const int quad = lane >> 4, l16 = lane & 15;
  const int b = blockIdx.y / NHEADS, h = blockIdx.y % NHEADS;
  const int q0 = blockIdx.x * 64;

  const size_t qrow = (size_t)(b * T + q0 + wid * 16 + l16);
  bf16x8 aq0 = *(const bf16x8*)&Q[qrow * HID + h * 64 + quad * 8];
  bf16x8 aq1 = *(const bf16x8*)&Q[qrow * HID + h * 64 + 32 + quad * 8];
#pragma unroll
  for (int j = 0; j < 8; j++) {
    aq0[j] = (__bf16)((float)aq0[j] * scale);
    aq1[j] = (__bf16)((float)aq1[j] * scale);
  }
  bf16x8 ones;
#pragma unroll
  for (int j = 0; j < 8; j++) ones[j] = (__bf16)1.0f;

  f32x4 oacc[4] = {};
  float m_i[4], l_i[4];
#pragma unroll
  for (int r = 0; r < 4; r++) { m_i[r] = -1.0e30f; l_i[r] = 0.f; }

  const int ntiles = (Sv + BS - 1) / BS;
  for (int t0 = 0; t0 < ntiles; ++t0) {
    const int srow0 = b * Sv + t0 * BS;
    __syncthreads();
#pragma unroll
    for (int c = 0; c < 4; ++c) {
      int slot = c * 256 + tid;
      int row = slot >> 3, p = slot & 7;
      int gsrc = p ^ (row & 7);
      g2lds16(Kb + (size_t)(srow0 + row) * HID + h * 64 + gsrc * 8,
              &Ks[(size_t)(c * 256 + wid * 64) * 8]);
    }
#pragma unroll
    for (int c = 0; c < 4; ++c) {
      int slot = c * 256 + tid;
      int srow = slot >> 3, scol = (slot & 7) * 8;
      union { uint4 u; u16 e[8]; } vv;
      vv.u = *(const uint4*)&Vb[(size_t)(srow0 + srow) * HID + h * 64 + scol];
      int g = srow >> 3, so = srow & 7;
#pragma unroll
      for (int j = 0; j < 8; j++) {
        int d = scol + j;
        int f = ((d >> 3) ^ d) & 7;
        Vt[d * BS + ((g ^ f) * 8 + so)] = vv.e[j];
      }
    }
    __syncthreads();

    f32x4 sc[8];
#pragma unroll
    for (int nt = 0; nt < 8; nt++) {
      int s = nt * 16 + l16;
      int fb = (s & 7);
      bf16x8 bk0 = *(const bf16x8*)&Ks[s * 64 + ((quad ^ fb) * 8)];
      bf16x8 bk1 = *(const bf16x8*)&Ks[s * 64 + (((quad ^ 4) ^ fb) * 8)];
      f32x4 z = {0.f, 0.f, 0.f, 0.f};
      z = __builtin_amdgcn_mfma_f32_16x16x32_bf16(aq0, bk0, z, 0, 0, 0);
      z = __builtin_amdgcn_mfma_f32_16x16x32_bf16(aq1, bk1, z, 0, 0, 0);
      sc[nt] = z;
    }
    if ((t0 == ntiles - 1) && (Sv & (BS - 1))) {
#pragma unroll
      for (int nt = 0; nt < 8; nt++) {
        int s = t0 * BS + nt * 16 + l16;
        if (s >= Sv)
#pragma unroll
          for (int r = 0; r < 4; r++) sc[nt][r] = -1.0e30f;
      }
    }
    float mnew[4];
#pragma unroll
    for (int r = 0; r < 4; r++) mnew[r] = m_i[r];
#pragma unroll
    for (int nt = 0; nt < 8; nt++)
#pragma unroll
      for (int r = 0; r < 4; r++) mnew[r] = fmaxf(mnew[r], sc[nt][r]);
#pragma unroll
    for (int off = 8; off >= 1; off >>= 1)
#pragma unroll
      for (int r = 0; r < 4; r++) mnew[r] = fmaxf(mnew[r], __shfl_xor(mnew[r], off));

    float alpha[4];
#pragma unroll
    for (int r = 0; r < 4; r++) alpha[r] = __expf(m_i[r] - mnew[r]);
#pragma unroll
    for (int nt = 0; nt < 8; nt++)
#pragma unroll
      for (int r = 0; r < 4; r++) sc[nt][r] = __expf(sc[nt][r] - mnew[r]);

#pragma unroll
    for (int nt = 0; nt < 8; nt++)
#pragma unroll
      for (int r = 0; r < 4; r++) {
        int row = quad * 4 + r, col = nt * 16 + l16;
        int g = col >> 3;
        Ps[wid][row * BS + ((g ^ (row & 7)) * 8 + (col & 7))] = f2b(sc[nt][r]);
      }
    bf16x8 pa[4];
#pragma unroll
    for (int kc = 0; kc < 4; kc++) {
      int lg = kc * 4 + quad;
      pa[kc] = *(const bf16x8*)&Ps[wid][l16 * BS + ((lg ^ (l16 & 7)) * 8)];
    }
    f32x4 ls = {0.f, 0.f, 0.f, 0.f};
#pragma unroll
    for (int kc = 0; kc < 4; kc++)
      ls = __builtin_amdgcn_mfma_f32_16x16x32_bf16(pa[kc], ones, ls, 0, 0, 0);
#pragma unroll
    for (int r = 0; r < 4; r++) {
      l_i[r] = l_i[r] * alpha[r] + ls[r];
      m_i[r] = mnew[r];
    }
#pragma unroll
    for (int dt = 0; dt < 4; dt++)
#pragma unroll
      for (int r = 0; r < 4; r++) oacc[dt][r] *= alpha[r];

#pragma unroll
    for (int dt = 0; dt < 4; dt++) {
      int d = dt * 16 + l16;
      int f = ((d >> 3) ^ d) & 7;
#pragma unroll
      for (int kc = 0; kc < 4; kc++) {
        int lg = kc * 4 + quad;
        bf16x8 bv = *(const bf16x8*)&Vt[d * BS + ((lg ^ f) * 8)];
        oacc[dt] = __builtin_amdgcn_mfma_f32_16x16x32_bf16(pa[kc], bv, oacc[dt], 0, 0, 0);
      }
    }
  }

#pragma unroll
  for (int dt = 0; dt < 4; dt++)
#pragma unroll
    for (int r = 0; r < 4; r++) {
      int row = b * T + q0 + wid * 16 + quad * 4 + r;
      int col = h * 64 + dt * 16 + l16;
      O[(size_t)row * HID + col] = f2b(oacc[dt][r] / l_i[r]);
    }
}

// ---------------------------------------------------------------------------
extern "C" void kernel_launch(void* const* d_in, const int* in_sizes, int n_in,
                              void* d_out, int out_size, void* d_ws, size_t ws_size,
                              hipStream_t stream) {
  const float* x    = (const float*)d_in[0];
  const float* enc  = (const float*)d_in[1];
  const float* ln1g = (const float*)d_in[2];
  const float* ln1b = (const float*)d_in[3];
  const float* ln2g = (const float*)d_in[4];
  const float* ln2b = (const float*)d_in[5];
  const float* ln3g = (const float*)d_in[6];
  const float* ln3b = (const float*)d_in[7];
  const float* wq1  = (const float*)d_in[8];
  const float* wk1  = (const float*)d_in[9];
  const float* wv1  = (const float*)d_in[10];
  const float* wo1  = (const float*)d_in[11];
  const float* bo1  = (const float*)d_in[12];
  const float* wq2  = (const float*)d_in[13];
  const float* wk2  = (const float*)d_in[14];
  const float* wv2  = (const float*)d_in[15];
  const float* wo2  = (const float*)d_in[16];
  const float* bo2  = (const float*)d_in[17];
  const float* wg   = (const float*)d_in[18];
  const float* bg   = (const float*)d_in[19];
  const float* wf   = (const float*)d_in[20];
  const float* bfo  = (const float*)d_in[21];
  float* out = (float*)d_out;

  const size_t S1 = 1280 * 1280;
  const size_t S2 = 1280 * 2048;
  const size_t SG = 10240 * 1280;
  const size_t SF = 1280 * 5120;
  const size_t ACT = (size_t)4096 * 1280;

  char* ws = (char*)d_ws;
  size_t off = 0;
  auto alloc = [&](size_t bytes) -> void* {
    void* p = ws + off;
    off += (bytes + 255) & ~(size_t)255;
    return p;
  };
  u16* wq1b = (u16*)alloc(S1 * 2);
  u16* wk1b = (u16*)alloc(S1 * 2);
  u16* wv1b = (u16*)alloc(S1 * 2);
  u16* wo1b = (u16*)alloc(S1 * 2);
  u16* wq2b = (u16*)alloc(S1 * 2);
  u16* wk2b = (u16*)alloc(S2 * 2);
  u16* wv2b = (u16*)alloc(S2 * 2);
  u16* wo2b = (u16*)alloc(S1 * 2);
  u16* wgb  = (u16*)alloc(SG * 2);
  u16* wfb  = (u16*)alloc(SF * 2);
  u16* h    = (u16*)alloc(ACT * 2);
  u16* q    = (u16*)alloc(ACT * 2);
  u16* k    = (u16*)alloc(ACT * 2);
  u16* v    = (u16*)alloc(ACT * 2);
  u16* o    = (u16*)alloc(ACT * 2);
  u16* ffin = q;                      // 4096x5120 bf16 == q+k+v+o exactly
  u16* k2   = (u16*)alloc((size_t)256 * 1280 * 2);
  u16* v2   = (u16*)alloc((size_t)256 * 1280 * 2);
  u16* encp = (u16*)alloc((size_t)256 * 2048 * 2);
  float* x2 = out;
  float* x3 = (float*)alloc(ACT * 4);
  (void)k; (void)v; (void)ws_size; (void)in_sizes; (void)n_in; (void)out_size;

  CvtArgs ca;
  const float* srcs[10] = {wq1, wk1, wv1, wo1, wq2, wk2, wv2, wo2, wg, wf};
  u16* dsts[10] = {wq1b, wk1b, wv1b, wo1b, wq2b, wk2b, wv2b, wo2b, wgb, wfb};
  int n4s[10] = {(int)(S1/4), (int)(S1/4), (int)(S1/4), (int)(S1/4), (int)(S1/4),
                 (int)(S2/4), (int)(S2/4), (int)(S1/4), (int)(SG/4), (int)(SF/4)};
  ca.cum4[0] = 0;
  for (int i = 0; i < 10; i++) { ca.src[i] = srcs[i]; ca.dst[i] = dsts[i]; ca.cum4[i+1] = ca.cum4[i] + n4s[i]; }
  int total4 = ca.cum4[10];
  cvt_weights<<<(total4 + 255) / 256, 256, 0, stream>>>(ca, total4);
  cvt_enc<<<512, 256, 0, stream>>>(enc, encp);

  ln_bf16<<<4096, 256, 0, stream>>>(x, ln1g, ln1b, h);
  gemm_bt<<<dim3(30, 32), 256, 0, stream>>>(h, wq1b, q, nullptr, nullptr, nullptr,
                                            4096, 3840, 1280, 0, 1280);
  flash_attn<<<dim3(32, 40), 256, 0, stream>>>(q, k, v, o, 2048, 2048, 0.125f);
  gemm_bt<<<dim3(10, 32), 256, 0, stream>>>(o, wo1b, nullptr, x2, bo1, x,
                                            4096, 1280, 1280, 1, 0);
  ln_bf16<<<4096, 256, 0, stream>>>(x2, ln2g, ln2b, h);
  gemm_bt<<<dim3(10, 32), 256, 0, stream>>>(h, wq2b, q, nullptr, nullptr, nullptr,
                                            4096, 1280, 1280, 0, 0);
  gemm_bt<<<dim3(20, 2), 256, 0, stream>>>(encp, wk2b, k2, nullptr, nullptr, nullptr,
                                           256, 2560, 2048, 0, 1280);
  flash_attn<<<dim3(32, 40), 256, 0, stream>>>(q, k2, v2, o, 2048, 77, 0.125f);
  gemm_bt<<<dim3(10, 32), 256, 0, stream>>>(o, wo2b, nullptr, x3, bo2, x2,
                                            4096, 1280, 1280, 1, 0);
  ln_bf16<<<4096, 256, 0, stream>>>(x3, ln3g, ln3b, h);
  gemm_geglu<<<dim3(80, 32), 256, 0, stream>>>(h, wgb, bg, ffin, 4096, 1280);
  gemm_bt<<<dim3(10, 32), 256, 0, stream>>>(ffin, wfb, nullptr, out, bfo, x3,
                                            4096, 1280, 5120, 1, 0);
}

// Round 5
// 807.148 us; speedup vs baseline: 1.1249x; 1.1249x over previous
//
#include <hip/hip_runtime.h>

typedef unsigned short u16;
typedef __bf16 bf16x8 __attribute__((ext_vector_type(8)));
typedef float f32x4 __attribute__((ext_vector_type(4)));

#define HID 1280
#define NHEADS 20
#define FFD 5120

__device__ __forceinline__ u16 f2b(float f) {
  union { float f; unsigned u; } a; a.f = f;
  unsigned r = a.u + 0x7FFFu + ((a.u >> 16) & 1u);
  return (u16)(r >> 16);
}

// gelu via tanh-form sigmoid: max abs err ~3e-4, invisible under bf16 store.
__device__ __forceinline__ float gelu_fast(float x) {
  float z = 1.5957691216f * (x + 0.044715f * x * x * x);
  return x / (1.0f + __expf(-z));
}

__device__ __forceinline__ void g2lds16(const void* g, void* l) {
  __builtin_amdgcn_global_load_lds(
      (__attribute__((address_space(1))) void*)(g),
      (__attribute__((address_space(3))) void*)(l), 16, 0, 0);
}

// Supertile swizzle (round-3 form — best measured FETCH): consecutive block
// ids walk adaptive sx*sy supertiles; footprint ~5 MB shared through L3.
__device__ __forceinline__ void swz(int& bx, int& by) {
  int nx = gridDim.x, ny = gridDim.y;
  int id = blockIdx.y * nx + blockIdx.x;
  int sx = ((nx & 7) == 0) ? 8 : (((nx & 3) == 0) ? 4 : (((nx & 1) == 0) ? 2 : 1));
  int sy = ((ny & 7) == 0) ? 8 : (((ny & 3) == 0) ? 4 : (((ny & 1) == 0) ? 2 : 1));
  int per = sx * sy;
  int st = id / per, w = id - st * per;
  int nsx = nx / sx;
  int stx = st % nsx, sty = st / nsx;
  bx = stx * sx + (w % sx);
  by = sty * sy + (w / sx);
}

// ---------------------------------------------------------------------------
struct CvtArgs {
  const float* src[10];
  u16* dst[10];
  int cum4[11];
};

__global__ __launch_bounds__(256) void cvt_weights(CvtArgs a, int total4) {
  int i = blockIdx.x * 256 + threadIdx.x;
  if (i >= total4) return;
  int seg = 0;
#pragma unroll
  for (int s = 1; s < 10; s++) seg += (i >= a.cum4[s]);
  int j = (i - a.cum4[seg]) * 4;
  float4 f = *(const float4*)(a.src[seg] + j);
  union { unsigned long long u; u16 s[4]; } o;
  o.s[0] = f2b(f.x); o.s[1] = f2b(f.y); o.s[2] = f2b(f.z); o.s[3] = f2b(f.w);
  *(unsigned long long*)(a.dst[seg] + j) = o.u;
}

__global__ __launch_bounds__(256) void cvt_enc(const float* __restrict__ enc,
                                               u16* __restrict__ encp) {
  int i = blockIdx.x * 256 + threadIdx.x;
  int j = i * 4;
  int row = j >> 11;
  unsigned long long out = 0ull;
  if (row < 154) {
    float4 f = *(const float4*)(enc + j);
    union { unsigned long long u; u16 s[4]; } o;
    o.s[0] = f2b(f.x); o.s[1] = f2b(f.y); o.s[2] = f2b(f.z); o.s[3] = f2b(f.w);
    out = o.u;
  }
  *(unsigned long long*)(encp + j) = out;
}

// ---------------------------------------------------------------------------
__global__ __launch_bounds__(256) void ln_bf16(const float* __restrict__ X,
                                               const float* __restrict__ g,
                                               const float* __restrict__ bta,
                                               u16* __restrict__ Out) {
  const int row = blockIdx.x, tid = threadIdx.x;
  const float* xr = X + (size_t)row * HID;
  float v[5];
#pragma unroll
  for (int i = 0; i < 5; i++) v[i] = xr[tid + i * 256];
  float s = v[0] + v[1] + v[2] + v[3] + v[4];
#pragma unroll
  for (int off = 32; off >= 1; off >>= 1) s += __shfl_down(s, off);
  __shared__ float red[4];
  if ((tid & 63) == 0) red[tid >> 6] = s;
  __syncthreads();
  float mu = (red[0] + red[1] + red[2] + red[3]) * (1.0f / HID);
  float d = 0.f;
#pragma unroll
  for (int i = 0; i < 5; i++) { float t = v[i] - mu; d += t * t; }
#pragma unroll
  for (int off = 32; off >= 1; off >>= 1) d += __shfl_down(d, off);
  __syncthreads();
  if ((tid & 63) == 0) red[tid >> 6] = d;
  __syncthreads();
  float rstd = rsqrtf((red[0] + red[1] + red[2] + red[3]) * (1.0f / HID) + 1e-5f);
#pragma unroll
  for (int i = 0; i < 5; i++) {
    int c = tid + i * 256;
    Out[(size_t)row * HID + c] = f2b((v[i] - mu) * rstd * g[c] + bta[c]);
  }
}

// ---------------------------------------------------------------------------
// bf16 GEMM, C = A * W^T. 128x128 tile, BK=64 (32 MFMAs per barrier, 20
// barriers at K=1280 — halves the vmcnt-drain count vs BK=32).
// LDS: 8 granules (16B) per row; phys granule p of row r holds logical
// p ^ (r&7). Within a quad's 16 lanes that's 2 lanes/slot = free.
// ---------------------------------------------------------------------------
__global__ __launch_bounds__(256) void gemm_bt(
    const u16* __restrict__ A, const u16* __restrict__ Bw,
    u16* __restrict__ Cb, float* __restrict__ Cf,
    const float* __restrict__ bias, const float* __restrict__ resid,
    int M, int N, int K, int mode, int nsplit) {
  __shared__ u16 As[8192];   // 128 x 64
  __shared__ u16 Bs[8192];   // 128 x 64
  const int tid = threadIdx.x;
  const int wid = tid >> 6, lane = tid & 63;
  const int quad = lane >> 4, l16 = lane & 15;
  int bx, by; swz(bx, by);
  const int bm = by * 128, bn = bx * 128;
  const int wm = (wid & 1) * 64, wn = (wid >> 1) * 64;

  // staging offsets (loop-invariant): granule g = c*256+tid
  size_t aoff[4], boff[4];
#pragma unroll
  for (int c = 0; c < 4; ++c) {
    int g = c * 256 + tid;
    int row = g >> 3, pg = g & 7;
    int sc = (pg ^ (row & 7)) * 8;
    aoff[c] = (size_t)(bm + row) * K + sc;
    boff[c] = (size_t)(bn + row) * K + sc;
  }

  f32x4 acc[4][4] = {};
  const int s7 = l16 & 7;

  for (int k0 = 0; k0 < K; k0 += 64) {
    __syncthreads();
#pragma unroll
    for (int c = 0; c < 4; ++c) {
      g2lds16(A + aoff[c] + k0, &As[(c * 256 + wid * 64) * 8]);
      g2lds16(Bw + boff[c] + k0, &Bs[(c * 256 + wid * 64) * 8]);
    }
    __syncthreads();
#pragma unroll
    for (int kc = 0; kc < 2; kc++) {
      const int ph = ((kc << 2) + quad) ^ s7;
      bf16x8 af[4], bfr[4];
#pragma unroll
      for (int mt = 0; mt < 4; mt++)
        af[mt] = *(const bf16x8*)&As[(wm + mt * 16 + l16) * 64 + ph * 8];
#pragma unroll
      for (int nt = 0; nt < 4; nt++)
        bfr[nt] = *(const bf16x8*)&Bs[(wn + nt * 16 + l16) * 64 + ph * 8];
#pragma unroll
      for (int mt = 0; mt < 4; mt++)
#pragma unroll
        for (int nt = 0; nt < 4; nt++)
          acc[mt][nt] = __builtin_amdgcn_mfma_f32_16x16x32_bf16(af[mt], bfr[nt], acc[mt][nt], 0, 0, 0);
    }
  }

  if (mode == 0) {
#pragma unroll
    for (int mt = 0; mt < 4; mt++)
#pragma unroll
      for (int nt = 0; nt < 4; nt++)
#pragma unroll
        for (int r = 0; r < 4; r++) {
          int row = bm + wm + mt * 16 + quad * 4 + r;
          int col = bn + wn + nt * 16 + l16;
          u16 val = f2b(acc[mt][nt][r]);
          if (nsplit > 0) {
            int t = (col >= 2 * nsplit) ? 2 : ((col >= nsplit) ? 1 : 0);
            int dc = col - t * nsplit;
            Cb[(size_t)t * M * nsplit + (size_t)row * nsplit + dc] = val;
          } else {
            Cb[(size_t)row * N + col] = val;
          }
        }
  } else {
#pragma unroll
    for (int mt = 0; mt < 4; mt++)
#pragma unroll
      for (int nt = 0; nt < 4; nt++)
#pragma unroll
        for (int r = 0; r < 4; r++) {
          int row = bm + wm + mt * 16 + quad * 4 + r;
          int col = bn + wn + nt * 16 + l16;
          size_t idx = (size_t)row * N + col;
          Cf[idx] = acc[mt][nt][r] + bias[col] + resid[idx];
        }
  }
}

// ---------------------------------------------------------------------------
// GEGLU GEMM: 128M x 64N dual-gate, BK=64, same swizzle, fast-gelu epilogue.
// ---------------------------------------------------------------------------
__global__ __launch_bounds__(256) void gemm_geglu(
    const u16* __restrict__ A, const u16* __restrict__ W,
    const float* __restrict__ bias, u16* __restrict__ Out,
    int M, int K) {
  __shared__ u16 As[8192];    // 128 x 64
  __shared__ u16 B1s[4096];   // 64 x 64
  __shared__ u16 B2s[4096];   // 64 x 64
  const int tid = threadIdx.x;
  const int wid = tid >> 6, lane = tid & 63;
  const int quad = lane >> 4, l16 = lane & 15;
  int bx, by; swz(bx, by);
  const int bm = by * 128, bn = bx * 64;
  const int wm = (wid & 1) * 64, wn = (wid >> 1) * 32;

  size_t aoff[4], b1off[2], b2off[2];
#pragma unroll
  for (int c = 0; c < 4; ++c) {
    int g = c * 256 + tid;
    int row = g >> 3, pg = g & 7;
    int sc = (pg ^ (row & 7)) * 8;
    aoff[c] = (size_t)(bm + row) * K + sc;
    if (c < 2) {
      b1off[c] = (size_t)(bn + row) * K + sc;
      b2off[c] = (size_t)(FFD + bn + row) * K + sc;
    }
  }

  f32x4 acc1[4][2] = {};
  f32x4 acc2[4][2] = {};
  const int s7 = l16 & 7;

  for (int k0 = 0; k0 < K; k0 += 64) {
    __syncthreads();
#pragma unroll
    for (int c = 0; c < 4; ++c)
      g2lds16(A + aoff[c] + k0, &As[(c * 256 + wid * 64) * 8]);
#pragma unroll
    for (int c = 0; c < 2; ++c) {
      g2lds16(W + b1off[c] + k0, &B1s[(c * 256 + wid * 64) * 8]);
      g2lds16(W + b2off[c] + k0, &B2s[(c * 256 + wid * 64) * 8]);
    }
    __syncthreads();
#pragma unroll
    for (int kc = 0; kc < 2; kc++) {
      const int ph = ((kc << 2) + quad) ^ s7;
      bf16x8 af[4], b1[2], b2[2];
#pragma unroll
      for (int mt = 0; mt < 4; mt++)
        af[mt] = *(const bf16x8*)&As[(wm + mt * 16 + l16) * 64 + ph * 8];
#pragma unroll
      for (int nt = 0; nt < 2; nt++) {
        b1[nt] = *(const bf16x8*)&B1s[(wn + nt * 16 + l16) * 64 + ph * 8];
        b2[nt] = *(const bf16x8*)&B2s[(wn + nt * 16 + l16) * 64 + ph * 8];
      }
#pragma unroll
      for (int mt = 0; mt < 4; mt++)
#pragma unroll
        for (int nt = 0; nt < 2; nt++) {
          acc1[mt][nt] = __builtin_amdgcn_mfma_f32_16x16x32_bf16(af[mt], b1[nt], acc1[mt][nt], 0, 0, 0);
          acc2[mt][nt] = __builtin_amdgcn_mfma_f32_16x16x32_bf16(af[mt], b2[nt], acc2[mt][nt], 0, 0, 0);
        }
    }
  }

#pragma unroll
  for (int mt = 0; mt < 4; mt++)
#pragma unroll
    for (int nt = 0; nt < 2; nt++)
#pragma unroll
      for (int r = 0; r < 4; r++) {
        int row = bm + wm + mt * 16 + quad * 4 + r;
        int col = bn + wn + nt * 16 + l16;
        float v1 = acc1[mt][nt][r] + bias[col];
        float v2 = acc2[mt][nt][r] + bias[FFD + col];
        Out[(size_t)row * FFD + col] = f2b(v1 * gelu_fast(v2));
      }
}

// ---------------------------------------------------------------------------
// Flash attention (round-3 version, conflicts already near-zero).
// ---------------------------------------------------------------------------
#define BS 128
__global__ __launch_bounds__(256) void flash_attn(
    const u16* __restrict__ Q, const u16* __restrict__ Kb,
    const u16* __restrict__ Vb, u16* __restrict__ O,
    int T, int Sv, float scale) {
  __shared__ u16 Ks[BS * 64];
  __shared__ u16 Vt[64 * BS];
  __shared__ u16 Ps[4][16 * BS];
  const int tid = threadIdx.x, wid = tid >> 6, lane = tid & 63;
  const int quad = lane >> 4, l16 = lane & 15;
  const int b = blockIdx.y / NHEADS, h = blockIdx.y % NHEADS;
  const int q0 = blockIdx.x * 64;

  const size_t qrow = (size_t)(b * T + q0 + wid * 16 + l16);
  bf16x8 aq0 = *(const bf16x8*)&Q[qrow * HID + h * 64 + quad * 8];
  bf16x8 aq1 = *(const bf16x8*)&Q[qrow * HID + h * 64 + 32 + quad * 8];
#pragma unroll
  for (int j = 0; j < 8; j++) {
    aq0[j] = (__bf16)((float)aq0[j] * scale);
    aq1[j] = (__bf16)((float)aq1[j] * scale);
  }
  bf16x8 ones;
#pragma unroll
  for (int j = 0; j < 8; j++) ones[j] = (__bf16)1.0f;

  f32x4 oacc[4] = {};
  float m_i[4], l_i[4];
#pragma unroll
  for (int r = 0; r < 4; r++) { m_i[r] = -1.0e30f; l_i[r] = 0.f; }

  const int ntiles = (Sv + BS - 1) / BS;
  for (int t0 = 0; t0 < ntiles; ++t0) {
    const int srow0 = b * Sv + t0 * BS;
    __syncthreads();
#pragma unroll
    for (int c = 0; c < 4; ++c) {
      int slot = c * 256 + tid;
      int row = slot >> 3, p = slot & 7;
      int gsrc = p ^ (row & 7);
      g2lds16(Kb + (size_t)(srow0 + row) * HID + h * 64 + gsrc * 8,
              &Ks[(size_t)(c * 256 + wid * 64) * 8]);
    }
#pragma unroll
    for (int c = 0; c < 4; ++c) {
      int slot = c * 256 + tid;
      int srow = slot >> 3, scol = (slot & 7) * 8;
      union { uint4 u; u16 e[8]; } vv;
      vv.u = *(const uint4*)&Vb[(size_t)(srow0 + srow) * HID + h * 64 + scol];
      int g = srow >> 3, so = srow & 7;
#pragma unroll
      for (int j = 0; j < 8; j++) {
        int d = scol + j;
        int f = ((d >> 3) ^ d) & 7;
        Vt[d * BS + ((g ^ f) * 8 + so)] = vv.e[j];
      }
    }
    __syncthreads();

    f32x4 sc[8];
#pragma unroll
    for (int nt = 0; nt < 8; nt++) {
      int s = nt * 16 + l16;
      int fb = (s & 7);
      bf16x8 bk0 = *(const bf16x8*)&Ks[s * 64 + ((quad ^ fb) * 8)];
      bf16x8 bk1 = *(const bf16x8*)&Ks[s * 64 + (((quad ^ 4) ^ fb) * 8)];
      f32x4 z = {0.f, 0.f, 0.f, 0.f};
      z = __builtin_amdgcn_mfma_f32_16x16x32_bf16(aq0, bk0, z, 0, 0, 0);
      z = __builtin_amdgcn_mfma_f32_16x16x32_bf16(aq1, bk1, z, 0, 0, 0);
      sc[nt] = z;
    }
    if ((t0 == ntiles - 1) && (Sv & (BS - 1))) {
#pragma unroll
      for (int nt = 0; nt < 8; nt++) {
        int s = t0 * BS + nt * 16 + l16;
        if (s >= Sv)
#pragma unroll
          for (int r = 0; r < 4; r++) sc[nt][r] = -1.0e30f;
      }
    }
    float mnew[4];
#pragma unroll
    for (int r = 0; r < 4; r++) mnew[r] = m_i[r];
#pragma unroll
    for (int nt = 0; nt < 8; nt++)
#pragma unroll
      for (int r = 0; r < 4; r++) mnew[r] = fmaxf(mnew[r], sc[nt][r]);
#pragma unroll
    for (int off = 8; off >= 1; off >>= 1)
#pragma unroll
      for (int r = 0; r < 4; r++) mnew[r] = fmaxf(mnew[r], __shfl_xor(mnew[r], off));

    float alpha[4];
#pragma unroll
    for (int r = 0; r < 4; r++) alpha[r] = __expf(m_i[r] - mnew[r]);
#pragma unroll
    for (int nt = 0; nt < 8; nt++)
#pragma unroll
      for (int r = 0; r < 4; r++) sc[nt][r] = __expf(sc[nt][r] - mnew[r]);

#pragma unroll
    for (int nt = 0; nt < 8; nt++)
#pragma unroll
      for (int r = 0; r < 4; r++) {
        int row = quad * 4 + r, col = nt * 16 + l16;
        int g = col >> 3;
        Ps[wid][row * BS + ((g ^ (row & 7)) * 8 + (col & 7))] = f2b(sc[nt][r]);
      }
    bf16x8 pa[4];
#pragma unroll
    for (int kc = 0; kc < 4; kc++) {
      int lg = kc * 4 + quad;
      pa[kc] = *(const bf16x8*)&Ps[wid][l16 * BS + ((lg ^ (l16 & 7)) * 8)];
    }
    f32x4 ls = {0.f, 0.f, 0.f, 0.f};
#pragma unroll
    for (int kc = 0; kc < 4; kc++)
      ls = __builtin_amdgcn_mfma_f32_16x16x32_bf16(pa[kc], ones, ls, 0, 0, 0);
#pragma unroll
    for (int r = 0; r < 4; r++) {
      l_i[r] = l_i[r] * alpha[r] + ls[r];
      m_i[r] = mnew[r];
    }
#pragma unroll
    for (int dt = 0; dt < 4; dt++)
#pragma unroll
      for (int r = 0; r < 4; r++) oacc[dt][r] *= alpha[r];

#pragma unroll
    for (int dt = 0; dt < 4; dt++) {
      int d = dt * 16 + l16;
      int f = ((d >> 3) ^ d) & 7;
#pragma unroll
      for (int kc = 0; kc < 4; kc++) {
        int lg = kc * 4 + quad;
        bf16x8 bv = *(const bf16x8*)&Vt[d * BS + ((lg ^ f) * 8)];
        oacc[dt] = __builtin_amdgcn_mfma_f32_16x16x32_bf16(pa[kc], bv, oacc[dt], 0, 0, 0);
      }
    }
  }

#pragma unroll
  for (int dt = 0; dt < 4; dt++)
#pragma unroll
    for (int r = 0; r < 4; r++) {
      int row = b * T + q0 + wid * 16 + quad * 4 + r;
      int col = h * 64 + dt * 16 + l16;
      O[(size_t)row * HID + col] = f2b(oacc[dt][r] / l_i[r]);
    }
}

// ---------------------------------------------------------------------------
extern "C" void kernel_launch(void* const* d_in, const int* in_sizes, int n_in,
                              void* d_out, int out_size, void* d_ws, size_t ws_size,
                              hipStream_t stream) {
  const float* x    = (const float*)d_in[0];
  const float* enc  = (const float*)d_in[1];
  const float* ln1g = (const float*)d_in[2];
  const float* ln1b = (const float*)d_in[3];
  const float* ln2g = (const float*)d_in[4];
  const float* ln2b = (const float*)d_in[5];
  const float* ln3g = (const float*)d_in[6];
  const float* ln3b = (const float*)d_in[7];
  const float* wq1  = (const float*)d_in[8];
  const float* wk1  = (const float*)d_in[9];
  const float* wv1  = (const float*)d_in[10];
  const float* wo1  = (const float*)d_in[11];
  const float* bo1  = (const float*)d_in[12];
  const float* wq2  = (const float*)d_in[13];
  const float* wk2  = (const float*)d_in[14];
  const float* wv2  = (const float*)d_in[15];
  const float* wo2  = (const float*)d_in[16];
  const float* bo2  = (const float*)d_in[17];
  const float* wg   = (const float*)d_in[18];
  const float* bg   = (const float*)d_in[19];
  const float* wf   = (const float*)d_in[20];
  const float* bfo  = (const float*)d_in[21];
  float* out = (float*)d_out;

  const size_t S1 = 1280 * 1280;
  const size_t S2 = 1280 * 2048;
  const size_t SG = 10240 * 1280;
  const size_t SF = 1280 * 5120;
  const size_t ACT = (size_t)4096 * 1280;

  char* ws = (char*)d_ws;
  size_t off = 0;
  auto alloc = [&](size_t bytes) -> void* {
    void* p = ws + off;
    off += (bytes + 255) & ~(size_t)255;
    return p;
  };
  u16* wq1b = (u16*)alloc(S1 * 2);
  u16* wk1b = (u16*)alloc(S1 * 2);
  u16* wv1b = (u16*)alloc(S1 * 2);
  u16* wo1b = (u16*)alloc(S1 * 2);
  u16* wq2b = (u16*)alloc(S1 * 2);
  u16* wk2b = (u16*)alloc(S2 * 2);
  u16* wv2b = (u16*)alloc(S2 * 2);
  u16* wo2b = (u16*)alloc(S1 * 2);
  u16* wgb  = (u16*)alloc(SG * 2);
  u16* wfb  = (u16*)alloc(SF * 2);
  u16* h    = (u16*)alloc(ACT * 2);
  u16* q    = (u16*)alloc(ACT * 2);
  u16* k    = (u16*)alloc(ACT * 2);
  u16* v    = (u16*)alloc(ACT * 2);
  u16* o    = (u16*)alloc(ACT * 2);
  u16* ffin = q;                      // 4096x5120 bf16 == q+k+v+o exactly
  u16* k2   = (u16*)alloc((size_t)256 * 1280 * 2);
  u16* v2   = (u16*)alloc((size_t)256 * 1280 * 2);
  u16* encp = (u16*)alloc((size_t)256 * 2048 * 2);
  float* x2 = out;
  float* x3 = (float*)alloc(ACT * 4);
  (void)k; (void)v; (void)ws_size; (void)in_sizes; (void)n_in; (void)out_size;

  CvtArgs ca;
  const float* srcs[10] = {wq1, wk1, wv1, wo1, wq2, wk2, wv2, wo2, wg, wf};
  u16* dsts[10] = {wq1b, wk1b, wv1b, wo1b, wq2b, wk2b, wv2b, wo2b, wgb, wfb};
  int n4s[10] = {(int)(S1/4), (int)(S1/4), (int)(S1/4), (int)(S1/4), (int)(S1/4),
                 (int)(S2/4), (int)(S2/4), (int)(S1/4), (int)(SG/4), (int)(SF/4)};
  ca.cum4[0] = 0;
  for (int i = 0; i < 10; i++) { ca.src[i] = srcs[i]; ca.dst[i] = dsts[i]; ca.cum4[i+1] = ca.cum4[i] + n4s[i]; }
  int total4 = ca.cum4[10];
  cvt_weights<<<(total4 + 255) / 256, 256, 0, stream>>>(ca, total4);
  cvt_enc<<<512, 256, 0, stream>>>(enc, encp);

  ln_bf16<<<4096, 256, 0, stream>>>(x, ln1g, ln1b, h);
  gemm_bt<<<dim3(30, 32), 256, 0, stream>>>(h, wq1b, q, nullptr, nullptr, nullptr,
                                            4096, 3840, 1280, 0, 1280);
  flash_attn<<<dim3(32, 40), 256, 0, stream>>>(q, k, v, o, 2048, 2048, 0.125f);
  gemm_bt<<<dim3(10, 32), 256, 0, stream>>>(o, wo1b, nullptr, x2, bo1, x,
                                            4096, 1280, 1280, 1, 0);
  ln_bf16<<<4096, 256, 0, stream>>>(x2, ln2g, ln2b, h);
  gemm_bt<<<dim3(10, 32), 256, 0, stream>>>(h, wq2b, q, nullptr, nullptr, nullptr,
                                            4096, 1280, 1280, 0, 0);
  gemm_bt<<<dim3(20, 2), 256, 0, stream>>>(encp, wk2b, k2, nullptr, nullptr, nullptr,
                                           256, 2560, 2048, 0, 1280);
  flash_attn<<<dim3(32, 40), 256, 0, stream>>>(q, k2, v2, o, 2048, 77, 0.125f);
  gemm_bt<<<dim3(10, 32), 256, 0, stream>>>(o, wo2b, nullptr, x3, bo2, x2,
                                            4096, 1280, 1280, 1, 0);
  ln_bf16<<<4096, 256, 0, stream>>>(x3, ln3g, ln3b, h);
  gemm_geglu<<<dim3(80, 32), 256, 0, stream>>>(h, wgb, bg, ffin, 4096, 1280);
  gemm_bt<<<dim3(10, 32), 256, 0, stream>>>(ffin, wfb, nullptr, out, bfo, x3,
                                            4096, 1280, 5120, 1, 0);
}